// Round 19
// baseline (177.661 us; speedup 1.0000x reference)
//
#include <hip/hip_runtime.h>
#include <hip/hip_bf16.h>

// Problem constants (fixed by setup_inputs)
#define DIMC 1024
#define HC   16
#define DC   64
#define BC   4
#define SC   4096
#define ANC  512          // num_anchor_tokens
#define QNC  3584         // S - A
#define GK   1024         // K-dim of every GEMM (= DIMC)
#define QSCALE (0.125f * 1.44269504088896f)

typedef __attribute__((ext_vector_type(4))) float f32x4;
typedef __attribute__((ext_vector_type(8))) short s16x8;
typedef __attribute__((ext_vector_type(4))) short s16x4;

__device__ inline short f2bf(float f) {
    unsigned u = __builtin_bit_cast(unsigned, f);
    u += 0x7fff + ((u >> 16) & 1);          // RNE
    return (short)(u >> 16);
}
__device__ inline unsigned cvtpk(float lo, float hi) {   // RNE pack, same as f2bf
    unsigned d;
    asm("v_cvt_pk_bf16_f32 %0, %1, %2" : "=v"(d) : "v"(lo), "v"(hi));
    return d;
}

#define GLOAD16(gp, lp) __builtin_amdgcn_global_load_lds( \
    (const __attribute__((address_space(1))) void*)(gp),  \
    (__attribute__((address_space(3))) void*)(lp), 16, 0, 0)

// ---------------- pre-pass: 3 weight transposes only ----------------
__device__ __forceinline__ void tc_tile(
    const float* __restrict__ W, short* __restrict__ Wt, int K, int N,
    int bx, int by, float (*t)[33])
{
    const int tx = threadIdx.x & 31, ty = threadIdx.x >> 5;  // 32 x 8
    const int nt = bx * 32, kt = by * 32;
    #pragma unroll
    for (int j = 0; j < 4; ++j)
        t[ty + 8 * j][tx] = W[(size_t)(kt + ty + 8 * j) * N + nt + tx];
    __syncthreads();
    #pragma unroll
    for (int j = 0; j < 4; ++j)
        Wt[(size_t)(nt + ty + 8 * j) * K + kt + tx] = f2bf(t[tx][ty + 8 * j]);
}

__global__ __launch_bounds__(256) void prepass(
    const float* __restrict__ Wqkv, short* __restrict__ Wqkvt,
    const float* __restrict__ Wq, short* __restrict__ Wqt,
    const float* __restrict__ Wproj, short* __restrict__ Wprojt)
{
    __shared__ float t[32][33];
    const int b = blockIdx.x;
    if (b < 3072) {
        tc_tile(Wqkv, Wqkvt, 1024, 3072, b % 96, b / 96, t);
    } else {
        const int z = b - 3072;
        const float* W = (z < 1024) ? Wq : Wproj;
        short* Wt = (z < 1024) ? Wqt : Wprojt;
        const int zz = z & 1023;
        tc_tile(W, Wt, 1024, 1024, zz & 31, zz >> 5, t);
    }
}

// ---------------- k1k2 GEMM: A = f32 x, reg-staged + cvtpk; B bf16 gload_lds --
// R18 structure + T5 setprio around the MFMA cluster (3 blocks/CU at
// independent phase offsets -> inter-block role diversity for the scheduler).
__global__ __launch_bounds__(256, 3) void gemm_k1k2(
    const float* __restrict__ x,
    const short* __restrict__ Wqkvt, const float* __restrict__ bqkv,
    const short* __restrict__ Wqt,   const float* __restrict__ bq,
    short* __restrict__ Qb, short* __restrict__ Kb, short* __restrict__ Vtb)
{
    __shared__ __align__(16) char AB[49152];    // A bufs [0,24K), B [24K,48K)

    const int tid = threadIdx.x;
    const int wave = tid >> 6, lane = tid & 63;
    const int q = lane & 15, g = lane >> 4;
    const int wm = wave >> 1, wn = wave & 1;

    const int i = blockIdx.x;
    const char* ArowF; const char* Brow0; const float* bias;
    int bb, blocal, rowOff, bn, mode;
    if (i < 384) {                    // K1: anchors @ Wqkv
        const int c = i & 7, j = i >> 3;
        bn = (j % 24) * 128;
        const int bm = ((j / 24) * 8 + c) * 128;
        bb = bm / ANC; blocal = bm % ANC; rowOff = 0; mode = 0;
        ArowF = (const char*)(x + ((size_t)bb * SC + blocal) * DIMC);
        Brow0 = (const char*)(Wqkvt + (size_t)bn * GK);
        bias = bqkv;
    } else {                          // K2: queries @ Wq
        const int i2 = i - 384;
        const int c = i2 & 7, j = i2 >> 3;
        bn = (j % 8) * 128;
        const int bm = ((j / 8) * 8 + c) * 128;
        bb = bm / QNC; blocal = bm % QNC; rowOff = ANC; mode = 1;
        ArowF = (const char*)(x + ((size_t)bb * SC + ANC + blocal) * DIMC);
        Brow0 = (const char*)(Wqt + (size_t)bn * GK);
        bias = bq;
    }

    int srcF[2], srcB[2], dstOff[2];
    #pragma unroll
    for (int p = 0; p < 2; ++p) {
        const int ca = p * 256 + tid;
        const int row = ca >> 2;
        const int c = (ca & 3) ^ ((row >> 1) & 3);   // pre-swizzled chunk
        srcF[p] = row * 4096 + c * 32;               // f32 source (32B / chunk)
        srcB[p] = row * (GK * 2) + c * 16;           // bf16 source
        dstOff[p] = ca * 16;                         // linear LDS dest
    }

    f32x4 acc[4][4];
    #pragma unroll
    for (int a = 0; a < 4; ++a)
        #pragma unroll
        for (int b2 = 0; b2 < 4; ++b2) acc[a][b2] = (f32x4){0.f, 0.f, 0.f, 0.f};

    const int rc = ((g ^ ((q >> 1) & 3)) << 4);      // lane-constant read chunk

    float4 rA[3][4];   // 3 A-reg sets (all indices compile-time constants)

#define ISSB(bufi, kt) do {                                             \
        char* bb_ = AB + 24576 + (bufi) * 8192;                         \
        GLOAD16(Brow0 + srcB[0] + (kt) * 64, bb_ + dstOff[0]);          \
        GLOAD16(Brow0 + srcB[1] + (kt) * 64, bb_ + dstOff[1]);          \
    } while (0)

#define ISSA(s, kt) do {                                                \
        rA[s][0] = *(const float4*)(ArowF + srcF[0] + (kt) * 128);      \
        rA[s][1] = *(const float4*)(ArowF + srcF[0] + (kt) * 128 + 16); \
        rA[s][2] = *(const float4*)(ArowF + srcF[1] + (kt) * 128);      \
        rA[s][3] = *(const float4*)(ArowF + srcF[1] + (kt) * 128 + 16); \
    } while (0)

#define WRA(bufi, s) do {                                               \
        char* ab_ = AB + (bufi) * 8192;                                 \
        union { s16x8 v; unsigned u[4]; } w0, w1;                       \
        w0.u[0] = cvtpk(rA[s][0].x, rA[s][0].y);                        \
        w0.u[1] = cvtpk(rA[s][0].z, rA[s][0].w);                        \
        w0.u[2] = cvtpk(rA[s][1].x, rA[s][1].y);                        \
        w0.u[3] = cvtpk(rA[s][1].z, rA[s][1].w);                        \
        w1.u[0] = cvtpk(rA[s][2].x, rA[s][2].y);                        \
        w1.u[1] = cvtpk(rA[s][2].z, rA[s][2].w);                        \
        w1.u[2] = cvtpk(rA[s][3].x, rA[s][3].y);                        \
        w1.u[3] = cvtpk(rA[s][3].z, rA[s][3].w);                        \
        *(s16x8*)(ab_ + dstOff[0]) = w0.v;                              \
        *(s16x8*)(ab_ + dstOff[1]) = w1.v;                              \
    } while (0)

#define COMPUTE(bufi) do {                                              \
        const char* ab_ = AB + (bufi) * 8192;                           \
        const char* bb_ = AB + 24576 + (bufi) * 8192;                   \
        s16x8 aF[4], bF[4];                                             \
        _Pragma("unroll")                                               \
        for (int mi = 0; mi < 4; ++mi)                                  \
            aF[mi] = *(const s16x8*)(ab_ + (wm * 64 + mi * 16 + q) * 64 + rc); \
        _Pragma("unroll")                                               \
        for (int ni = 0; ni < 4; ++ni)                                  \
            bF[ni] = *(const s16x8*)(bb_ + (wn * 64 + ni * 16 + q) * 64 + rc); \
        __builtin_amdgcn_s_setprio(1);                                  \
        _Pragma("unroll")                                               \
        for (int mi = 0; mi < 4; ++mi)                                  \
            _Pragma("unroll")                                           \
            for (int ni = 0; ni < 4; ++ni)                              \
                acc[mi][ni] = __builtin_amdgcn_mfma_f32_16x16x32_bf16(  \
                    aF[mi], bF[ni], acc[mi][ni], 0, 0, 0);              \
        __builtin_amdgcn_s_setprio(0);                                  \
    } while (0)

#define PHF(cb, Bb, Wb, Ws, As, ktB, ktA) do {                          \
        asm volatile("s_waitcnt vmcnt(6)" ::: "memory");                \
        __builtin_amdgcn_s_barrier();                                   \
        WRA(Wb, Ws);          /* rA certified by the entry vmcnt(6) */  \
        ISSB(Bb, ktB);                                                  \
        ISSA(As, ktA);                                                  \
        COMPUTE(cb);                                                    \
    } while (0)

    // prologue: A(0)->set0, B(0), A(1)->set1, B(1), A(2)->set2; drain; write buf0
    ISSA(0, 0);
    ISSB(0, 0); ISSA(1, 1);
    ISSB(1, 1); ISSA(2, 2);
    asm volatile("s_waitcnt vmcnt(0)" ::: "memory");
    WRA(0, 0);
    asm volatile("s_waitcnt lgkmcnt(0)" ::: "memory");

    #pragma unroll 1
    for (int t = 0; t < 27; t += 3) {
        PHF(0, 2, 1, 1, 0, t + 2, t + 3);   // P=t
        PHF(1, 0, 2, 2, 1, t + 3, t + 4);   // P=t+1
        PHF(2, 1, 0, 0, 2, t + 4, t + 5);   // P=t+2
    }
    PHF(0, 2, 1, 1, 0, 29, 30);             // P=27
    PHF(1, 0, 2, 2, 1, 30, 31);             // P=28
    // P=29: write buf(30)=0 from set0 (A(30) certified); issue B(31); compute 2
    asm volatile("s_waitcnt vmcnt(6)" ::: "memory");
    __builtin_amdgcn_s_barrier();
    WRA(0, 0);
    ISSB(1, 31);
    COMPUTE(2);
    // P=30: certify phase-28 group (B(30)+A(31)); write buf(31)=1 from set1
    asm volatile("s_waitcnt vmcnt(2)" ::: "memory");
    __builtin_amdgcn_s_barrier();
    WRA(1, 1);
    COMPUTE(0);
    // P=31: drain all (B(31)); compute buf 1
    asm volatile("s_waitcnt vmcnt(0)" ::: "memory");
    __builtin_amdgcn_s_barrier();
    COMPUTE(1);

#undef PHF
#undef COMPUTE
#undef WRA
#undef ISSA
#undef ISSB

    // epilogue: lane holds C[wm*64+mi*16+4g+r][wn*64+ni*16+q]
    #pragma unroll
    for (int ni = 0; ni < 4; ++ni) {
        const int col = bn + wn * 64 + ni * 16 + q;
        const float bv = bias[col];
        #pragma unroll
        for (int mi = 0; mi < 4; ++mi) {
            const int rl0 = blocal + wm * 64 + mi * 16 + 4 * g;
            if (mode == 1) {
                const int h = col >> 6, d = col & 63;
                const size_t base = ((size_t)(bb * HC + h)) * SC + rowOff + rl0;
                #pragma unroll
                for (int r = 0; r < 4; ++r)
                    Qb[(base + r) * DC + d] = f2bf((acc[mi][ni][r] + bv) * QSCALE);
            } else {
                const int which = col >> 10;
                const int hd = col & 1023;
                const int h = hd >> 6, d = hd & 63;
                const size_t bh = (size_t)(bb * HC + h);
                if (which == 0) {
                    #pragma unroll
                    for (int r = 0; r < 4; ++r)
                        Qb[(bh * SC + rl0 + r) * DC + d] =
                            f2bf((acc[mi][ni][r] + bv) * QSCALE);
                } else if (which == 1) {
                    #pragma unroll
                    for (int r = 0; r < 4; ++r)
                        Kb[(bh * ANC + rl0 + r) * DC + d] = f2bf(acc[mi][ni][r] + bv);
                } else {
                    union { s16x4 v; unsigned long long d8; } pk;
                    #pragma unroll
                    for (int r = 0; r < 4; ++r) pk.v[r] = f2bf(acc[mi][ni][r] + bv);
                    *(unsigned long long*)(Vtb + (bh * DC + d) * ANC + rl0) = pk.d8;
                }
            }
        }
    }
}

// ---------------- proj GEMM (A bf16 via gload_lds) + T5 setprio ---------------
__global__ __launch_bounds__(256) void gemm_proj(
    const short* __restrict__ Abase, const short* __restrict__ Bt,
    const float* __restrict__ bias, float* __restrict__ outF)
{
    __shared__ __align__(16) char AB[49152];

    const int tid = threadIdx.x;
    const int wave = tid >> 6, lane = tid & 63;
    const int q = lane & 15, g = lane >> 4;
    const int wm = wave >> 1, wn = wave & 1;

    const int i = blockIdx.x;
    const int c0 = i & 7, j = i >> 3;
    const int bn = (j % 8) * 128;
    const int bm = ((j / 8) * 8 + c0) * 128;
    const char* Arow0 = (const char*)(Abase + (size_t)bm * GK);
    const char* Brow0 = (const char*)(Bt + (size_t)bn * GK);

    int srcOff[2], dstOff[2];
    #pragma unroll
    for (int p = 0; p < 2; ++p) {
        const int ca = p * 256 + tid;
        const int row = ca >> 2;
        const int c = (ca & 3) ^ ((row >> 1) & 3);
        srcOff[p] = row * (GK * 2) + c * 16;
        dstOff[p] = ca * 16;
    }

    f32x4 acc[4][4];
    #pragma unroll
    for (int a = 0; a < 4; ++a)
        #pragma unroll
        for (int b2 = 0; b2 < 4; ++b2) acc[a][b2] = (f32x4){0.f, 0.f, 0.f, 0.f};

    const int rc = ((g ^ ((q >> 1) & 3)) << 4);

#define STAGE(bufi, kt) do {                                            \
        const int kb_ = (kt) * 64;                                      \
        char* ab_ = AB + (bufi) * 8192;                                 \
        char* bb_ = AB + 24576 + (bufi) * 8192;                         \
        GLOAD16(Arow0 + srcOff[0] + kb_, ab_ + dstOff[0]);              \
        GLOAD16(Arow0 + srcOff[1] + kb_, ab_ + dstOff[1]);              \
        GLOAD16(Brow0 + srcOff[0] + kb_, bb_ + dstOff[0]);              \
        GLOAD16(Brow0 + srcOff[1] + kb_, bb_ + dstOff[1]);              \
    } while (0)

#define COMPUTE(bufi) do {                                              \
        const char* ab_ = AB + (bufi) * 8192;                           \
        const char* bb_ = AB + 24576 + (bufi) * 8192;                   \
        s16x8 aF[4], bF[4];                                             \
        _Pragma("unroll")                                               \
        for (int mi = 0; mi < 4; ++mi)                                  \
            aF[mi] = *(const s16x8*)(ab_ + (wm * 64 + mi * 16 + q) * 64 + rc); \
        _Pragma("unroll")                                               \
        for (int ni = 0; ni < 4; ++ni)                                  \
            bF[ni] = *(const s16x8*)(bb_ + (wn * 64 + ni * 16 + q) * 64 + rc); \
        __builtin_amdgcn_s_setprio(1);                                  \
        _Pragma("unroll")                                               \
        for (int mi = 0; mi < 4; ++mi)                                  \
            _Pragma("unroll")                                           \
            for (int ni = 0; ni < 4; ++ni)                              \
                acc[mi][ni] = __builtin_amdgcn_mfma_f32_16x16x32_bf16(  \
                    aF[mi], bF[ni], acc[mi][ni], 0, 0, 0);              \
        __builtin_amdgcn_s_setprio(0);                                  \
    } while (0)

#define PHASE4(stb, cb, kt) do {                                        \
        asm volatile("s_waitcnt vmcnt(4)" ::: "memory");                \
        __builtin_amdgcn_s_barrier();                                   \
        STAGE(stb, kt);                                                 \
        COMPUTE(cb);                                                    \
    } while (0)

    STAGE(0, 0);
    STAGE(1, 1);
    #pragma unroll 1
    for (int t = 0; t < 30; t += 3) {
        PHASE4(2, 0, t + 2);
        PHASE4(0, 1, t + 3);
        PHASE4(1, 2, t + 4);
    }
    asm volatile("s_waitcnt vmcnt(4)" ::: "memory");
    __builtin_amdgcn_s_barrier();
    COMPUTE(0);
    asm volatile("s_waitcnt vmcnt(0)" ::: "memory");
    __builtin_amdgcn_s_barrier();
    COMPUTE(1);
#undef PHASE4
#undef STAGE
#undef COMPUTE

    #pragma unroll
    for (int ni = 0; ni < 4; ++ni) {
        const int col = bn + wn * 64 + ni * 16 + q;
        const float bv = bias[col];
        #pragma unroll
        for (int mi = 0; mi < 4; ++mi) {
            const int grow = bm + wm * 64 + mi * 16 + 4 * g;
            #pragma unroll
            for (int r = 0; r < 4; ++r)
                outF[(size_t)(grow + r) * 1024 + col] = acc[mi][ni][r] + bv;
        }
    }
}

// ---------------- persistent-KV bf16 MFMA attention (R16-R18 exact) -----------
__global__ __launch_bounds__(512, 2) void attn_mfma(
    const short* __restrict__ Qb, const short* __restrict__ Kb,
    const short* __restrict__ Vtb, short* __restrict__ Aout)
{
    __shared__ __align__(16) char lds[147456];

    const int tid = threadIdx.x;
    const int wave = tid >> 6, lane = tid & 63;
    const int q = lane & 15, g = lane >> 4;
    const int q7 = q & 7;
    const int G = g ^ q7;
    const int bh = blockIdx.x >> 2;
    const int qc = blockIdx.x & 3;
    const int sbase = qc * 1024 + wave * 128;

    {
        const char* src = (const char*)(Kb + (size_t)bh * ANC * DC);
        #pragma unroll
        for (int l = 0; l < 8; ++l) {
            int i = l * 512 + tid;
            int row = i >> 3, cg = i & 7;
            union { float4 v; unsigned long long d[2]; } u;
            u.v = *(const float4*)(src + (size_t)i * 16);
            int kk = cg >> 2;
            int u0 = (2 * cg) & 7;
            int pc0 = 4 * kk + (u0 & 3);
            int hh = (u0 >> 2) << 3;
            int r7 = row & 7;
            char* dst = lds + row * 128;
            *(unsigned long long*)(dst + ((pc0 ^ r7) << 4) + hh) = u.d[0];
            *(unsigned long long*)(dst + (((pc0 + 1) ^ r7) << 4) + hh) = u.d[1];
        }
    }
    {
        const char* src = (const char*)(Vtb + (size_t)bh * DC * ANC);
        #pragma unroll
        for (int l = 0; l < 8; ++l) {
            int i = l * 512 + tid;
            int row = i >> 6, cg = i & 63;
            union { float4 v; unsigned long long d[2]; } u;
            u.v = *(const float4*)(src + (size_t)i * 16);
            int t2 = cg >> 2;
            int u0 = (2 * cg) & 7;
            int pc0 = 4 * t2 + (u0 & 3);
            int hh = (u0 >> 2) << 3;
            int r7 = row & 7;
            char* dst = lds + 65536 + row * 1024;
            *(unsigned long long*)(dst + ((pc0 ^ r7) << 4) + hh) = u.d[0];
            *(unsigned long long*)(dst + (((pc0 + 1) ^ r7) << 4) + hh) = u.d[1];
        }
    }
    __syncthreads();

    char* slot = lds + 131072 + wave * 2048;
    const int srow = lane >> 2, sc2 = lane & 3;
    const int sr7 = srow & 7;

    const int cgA = 2 * sc2, kkA = cgA >> 2, u0A = (2 * cgA) & 7;
    const int pcA = 4 * kkA + (u0A & 3), hA = (u0A >> 2) << 3;
    const int cgB = cgA + 1, kkB = cgB >> 2, u0B = (2 * cgB) & 7;
    const int pcB = 4 * kkB + (u0B & 3), hB = (u0B >> 2) << 3;
    const int wA0 = srow * 128 + ((pcA ^ sr7) << 4) + hA;
    const int wA1 = srow * 128 + (((pcA + 1) ^ sr7) << 4) + hA;
    const int wB0 = srow * 128 + ((pcB ^ sr7) << 4) + hB;
    const int wB1 = srow * 128 + (((pcB + 1) ^ sr7) << 4) + hB;
    const int wb0 = srow * 128 + (((sc2 * 2 + 0) ^ sr7) << 4);
    const int wb1 = srow * 128 + (((sc2 * 2 + 1) ^ sr7) << 4);
    const int sw = q7 << 4;

    const int off0 = G << 4, off1 = off0 ^ 64;
    const char* kb0 = lds + q * 128 + off0;
    const char* kb1 = lds + q * 128 + off1;
    const char* vregion = lds + 65536;
    const unsigned vo0 = (unsigned)((q +  0) * 1024 + off0);
    const unsigned vo1 = (unsigned)((q + 16) * 1024 + off0);
    const unsigned vo2 = (unsigned)((q + 32) * 1024 + off0);
    const unsigned vo3 = (unsigned)((q + 48) * 1024 + off0);

    const size_t qrow0 = (size_t)bh * SC;

    union { float4 v; unsigned long long d[2]; } gqA0, gqA1, gqB0, gqB1;
    {
        const char* QA = (const char*)(Qb + (qrow0 + sbase) * DC);
        gqA0.v = *(const float4*)(QA + lane * 32);
        gqA1.v = *(const float4*)(QA + lane * 32 + 16);
        const char* QB = QA + 16 * DC * 2;
        gqB0.v = *(const float4*)(QB + lane * 32);
        gqB1.v = *(const float4*)(QB + lane * 32 + 16);
    }

    for (int tp = 0; tp < 4; ++tp) {
        const int s0A = sbase + tp * 32;
        const int s0B = s0A + 16;

        *(unsigned long long*)(slot + wA0) = gqA0.d[0];
        *(unsigned long long*)(slot + wA1) = gqA0.d[1];
        *(unsigned long long*)(slot + wB0) = gqA1.d[0];
        *(unsigned long long*)(slot + wB1) = gqA1.d[1];
        __asm__ __volatile__("" ::: "memory");
        s16x8 qfA0 = *(const s16x8*)(slot + q * 128 + off0);
        s16x8 qfA1 = *(const s16x8*)(slot + q * 128 + off1);
        __asm__ __volatile__("" ::: "memory");
        *(unsigned long long*)(slot + wA0) = gqB0.d[0];
        *(unsigned long long*)(slot + wA1) = gqB0.d[1];
        *(unsigned long long*)(slot + wB0) = gqB1.d[0];
        *(unsigned long long*)(slot + wB1) = gqB1.d[1];
        __asm__ __volatile__("" ::: "memory");
        s16x8 qfB0 = *(const s16x8*)(slot + q * 128 + off0);
        s16x8 qfB1 = *(const s16x8*)(slot + q * 128 + off1);

        s16x8 pfA[16], pfB[16];
        float psA0 = 0.f, psA1 = 0.f, psA2 = 0.f, psA3 = 0.f;
        float psB0 = 0.f, psB1 = 0.f, psB2 = 0.f, psB3 = 0.f;
        __builtin_amdgcn_s_setprio(1);
        #pragma unroll
        for (int t2 = 0; t2 < 16; ++t2) {
            const int be = (2 * t2) * 2048, bo = be + 2048;
            s16x8 kfe0 = *(const s16x8*)(kb0 + be);
            s16x8 kfe1 = *(const s16x8*)(kb1 + be);
            f32x4 sA = (f32x4){0.f, 0.f, 0.f, 0.f};
            sA = __builtin_amdgcn_mfma_f32_16x16x32_bf16(kfe0, qfA0, sA, 0, 0, 0);
            sA = __builtin_amdgcn_mfma_f32_16x16x32_bf16(kfe1, qfA1, sA, 0, 0, 0);
            f32x4 sB = (f32x4){0.f, 0.f, 0.f, 0.f};
            sB = __builtin_amdgcn_mfma_f32_16x16x32_bf16(kfe0, qfB0, sB, 0, 0, 0);
            sB = __builtin_amdgcn_mfma_f32_16x16x32_bf16(kfe1, qfB1, sB, 0, 0, 0);
            s16x8 kfo0 = *(const s16x8*)(kb0 + bo);
            s16x8 kfo1 = *(const s16x8*)(kb1 + bo);
            f32x4 tA = (f32x4){0.f, 0.f, 0.f, 0.f};
            tA = __builtin_amdgcn_mfma_f32_16x16x32_bf16(kfo0, qfA0, tA, 0, 0, 0);
            tA = __builtin_amdgcn_mfma_f32_16x16x32_bf16(kfo1, qfA1, tA, 0, 0, 0);
            f32x4 tB = (f32x4){0.f, 0.f, 0.f, 0.f};
            tB = __builtin_amdgcn_mfma_f32_16x16x32_bf16(kfo0, qfB0, tB, 0, 0, 0);
            tB = __builtin_amdgcn_mfma_f32_16x16x32_bf16(kfo1, qfB1, tB, 0, 0, 0);

            float eA0 = exp2f(sA[0]), eA1 = exp2f(sA[1]);
            float eA2 = exp2f(sA[2]), eA3 = exp2f(sA[3]);
            float fA0 = exp2f(tA[0]), fA1 = exp2f(tA[1]);
            float fA2 = exp2f(tA[2]), fA3 = exp2f(tA[3]);
            psA0 += eA0 + fA0; psA1 += eA1 + fA1;
            psA2 += eA2 + fA2; psA3 += eA3 + fA3;
            float eB0 = exp2f(sB[0]), eB1 = exp2f(sB[1]);
            float eB2 = exp2f(sB[2]), eB3 = exp2f(sB[3]);
            float fB0 = exp2f(tB[0]), fB1 = exp2f(tB[1]);
            float fB2 = exp2f(tB[2]), fB3 = exp2f(tB[3]);
            psB0 += eB0 + fB0; psB1 += eB1 + fB1;
            psB2 += eB2 + fB2; psB3 += eB3 + fB3;

            union { s16x8 v; unsigned u[4]; } pkA, pkB;
            pkA.u[0] = cvtpk(eA0, eA1); pkA.u[1] = cvtpk(eA2, eA3);
            pkA.u[2] = cvtpk(fA0, fA1); pkA.u[3] = cvtpk(fA2, fA3);
            pfA[t2] = pkA.v;
            pkB.u[0] = cvtpk(eB0, eB1); pkB.u[1] = cvtpk(eB2, eB3);
            pkB.u[2] = cvtpk(fB0, fB1); pkB.u[3] = cvtpk(fB2, fB3);
            pfB[t2] = pkB.v;
        }
        __builtin_amdgcn_s_setprio(0);

        {
            const int snext = (tp < 3) ? (s0A + 32) : sbase;
            const char* QA = (const char*)(Qb + (qrow0 + snext) * DC);
            gqA0.v = *(const float4*)(QA + lane * 32);
            gqA1.v = *(const float4*)(QA + lane * 32 + 16);
            const char* QB = QA + 16 * DC * 2;
            gqB0.v = *(const float4*)(QB + lane * 32);
            gqB1.v = *(const float4*)(QB + lane * 32 + 16);
            __asm__ __volatile__("" :
                "+v"(gqA0.v.x), "+v"(gqA0.v.y), "+v"(gqA0.v.z), "+v"(gqA0.v.w),
                "+v"(gqA1.v.x), "+v"(gqA1.v.y), "+v"(gqA1.v.z), "+v"(gqA1.v.w),
                "+v"(gqB0.v.x), "+v"(gqB0.v.y), "+v"(gqB0.v.z), "+v"(gqB0.v.w),
                "+v"(gqB1.v.x), "+v"(gqB1.v.y), "+v"(gqB1.v.z), "+v"(gqB1.v.w));
        }

        float sumA = (psA0 + psA1) + (psA2 + psA3);
        sumA += __shfl_xor(sumA, 16);
        sumA += __shfl_xor(sumA, 32);
        const float rinvA = 1.0f / sumA;
        float sumB = (psB0 + psB1) + (psB2 + psB3);
        sumB += __shfl_xor(sumB, 16);
        sumB += __shfl_xor(sumB, 32);
        const float rinvB = 1.0f / sumB;

        f32x4 oaccA[4], oaccB[4];
        #pragma unroll
        for (int md = 0; md < 4; ++md) {
            oaccA[md] = (f32x4){0.f, 0.f, 0.f, 0.f};
            oaccB[md] = (f32x4){0.f, 0.f, 0.f, 0.f};
        }
        __builtin_amdgcn_s_setprio(1);
        #pragma unroll
        for (int t2 = 0; t2 < 16; ++t2) {
            const unsigned tx = (unsigned)(t2 << 6);
            s16x8 vf0 = *(const s16x8*)(vregion + (vo0 ^ tx));
            oaccA[0] = __builtin_amdgcn_mfma_f32_16x16x32_bf16(vf0, pfA[t2], oaccA[0], 0, 0, 0);
            oaccB[0] = __builtin_amdgcn_mfma_f32_16x16x32_bf16(vf0, pfB[t2], oaccB[0], 0, 0, 0);
            s16x8 vf1 = *(const s16x8*)(vregion + (vo1 ^ tx));
            oaccA[1] = __builtin_amdgcn_mfma_f32_16x16x32_bf16(vf1, pfA[t2], oaccA[1], 0, 0, 0);
            oaccB[1] = __builtin_amdgcn_mfma_f32_16x16x32_bf16(vf1, pfB[t2], oaccB[1], 0, 0, 0);
            s16x8 vf2 = *(const s16x8*)(vregion + (vo2 ^ tx));
            oaccA[2] = __builtin_amdgcn_mfma_f32_16x16x32_bf16(vf2, pfA[t2], oaccA[2], 0, 0, 0);
            oaccB[2] = __builtin_amdgcn_mfma_f32_16x16x32_bf16(vf2, pfB[t2], oaccB[2], 0, 0, 0);
            s16x8 vf3 = *(const s16x8*)(vregion + (vo3 ^ tx));
            oaccA[3] = __builtin_amdgcn_mfma_f32_16x16x32_bf16(vf3, pfA[t2], oaccA[3], 0, 0, 0);
            oaccB[3] = __builtin_amdgcn_mfma_f32_16x16x32_bf16(vf3, pfB[t2], oaccB[3], 0, 0, 0);
        }
        __builtin_amdgcn_s_setprio(0);

        __asm__ __volatile__("" ::: "memory");
        #pragma unroll
        for (int md = 0; md < 4; ++md) {
            union { unsigned long long d; unsigned u[2]; } ow;
            ow.u[0] = cvtpk(oaccA[md][0] * rinvA, oaccA[md][1] * rinvA);
            ow.u[1] = cvtpk(oaccA[md][2] * rinvA, oaccA[md][3] * rinvA);
            *(unsigned long long*)(slot + q * 128 + ((32 * md + 8 * g) ^ sw)) = ow.d;
        }
        __asm__ __volatile__("" ::: "memory");
        {
            float4 o0 = *(const float4*)(slot + wb0);
            float4 o1 = *(const float4*)(slot + wb1);
            char* Op = (char*)Aout +
                (((size_t)(bh >> 4) * SC + s0A + srow) * DIMC + (bh & 15) * DC) * 2 +
                sc2 * 32;
            *(float4*)(Op) = o0;
            *(float4*)(Op + 16) = o1;
        }
        __asm__ __volatile__("" ::: "memory");
        #pragma unroll
        for (int md = 0; md < 4; ++md) {
            union { unsigned long long d; unsigned u[2]; } ow;
            ow.u[0] = cvtpk(oaccB[md][0] * rinvB, oaccB[md][1] * rinvB);
            ow.u[1] = cvtpk(oaccB[md][2] * rinvB, oaccB[md][3] * rinvB);
            *(unsigned long long*)(slot + q * 128 + ((32 * md + 8 * g) ^ sw)) = ow.d;
        }
        __asm__ __volatile__("" ::: "memory");
        {
            float4 o0 = *(const float4*)(slot + wb0);
            float4 o1 = *(const float4*)(slot + wb1);
            char* Op = (char*)Aout +
                (((size_t)(bh >> 4) * SC + s0B + srow) * DIMC + (bh & 15) * DC) * 2 +
                sc2 * 32;
            *(float4*)(Op) = o0;
            *(float4*)(Op + 16) = o1;
        }
    }
}

// ---------------- launcher ----------------
extern "C" void kernel_launch(void* const* d_in, const int* in_sizes, int n_in,
                              void* d_out, int out_size, void* d_ws, size_t ws_size,
                              hipStream_t stream)
{
    (void)in_sizes; (void)n_in; (void)out_size; (void)ws_size;

    const float* x     = (const float*)d_in[0];
    const float* Wqkv  = (const float*)d_in[1];
    const float* bqkv  = (const float*)d_in[2];
    const float* Wq    = (const float*)d_in[3];
    const float* bq    = (const float*)d_in[4];
    const float* Wproj = (const float*)d_in[5];
    const float* bproj = (const float*)d_in[6];

    // d_out scratch: [unused 33.5MB | Qb bf16 33.5MB] (dead before proj writes)
    short* Qb = (short*)d_out + (size_t)16777216;
    short* Kb     = (short*)d_ws;
    short* Vtb    = Kb  + (size_t)2097152;
    short* Ab     = Vtb + (size_t)2097152;
    short* Wqkvt  = Ab  + (size_t)16777216;
    short* Wqt    = Wqkvt + (size_t)3145728;
    short* Wprojt = Wqt   + (size_t)1048576;

    // pre-pass: weight transposes only (k1k2 reads f32 x directly)
    prepass<<<dim3(5120), dim3(256), 0, stream>>>(
        Wqkv, Wqkvt, Wq, Wqt, Wproj, Wprojt);

    // K1+K2 fused: anchors @ Wqkv -> Qb/Kb/Vtb, queries @ Wq -> Qb (A = f32 x)
    gemm_k1k2<<<dim3(1280), dim3(256), 0, stream>>>(
        x, Wqkvt, bqkv, Wqt, bq, Qb, Kb, Vtb);

    // K3: persistent-KV MFMA attention -> Ab (bf16)
    attn_mfma<<<dim3(256), dim3(512), 0, stream>>>(Qb, Kb, Vtb, Ab);

    // K4: Ab @ Wproj + bproj -> d_out (fp32)
    gemm_proj<<<dim3(1024), dim3(256), 0, stream>>>(Ab, Wprojt, bproj, (float*)d_out);
}

// Round 20
// 170.273 us; speedup vs baseline: 1.0434x; 1.0434x over previous
//
#include <hip/hip_runtime.h>
#include <hip/hip_bf16.h>

// Problem constants (fixed by setup_inputs)
#define DIMC 1024
#define HC   16
#define DC   64
#define BC   4
#define SC   4096
#define ANC  512          // num_anchor_tokens
#define QNC  3584         // S - A
#define GK   1024         // K-dim of every GEMM (= DIMC)
#define QSCALE (0.125f * 1.44269504088896f)

typedef __attribute__((ext_vector_type(4))) float f32x4;
typedef __attribute__((ext_vector_type(8))) short s16x8;
typedef __attribute__((ext_vector_type(4))) short s16x4;

__device__ inline short f2bf(float f) {
    unsigned u = __builtin_bit_cast(unsigned, f);
    u += 0x7fff + ((u >> 16) & 1);          // RNE
    return (short)(u >> 16);
}
__device__ inline unsigned cvtpk(float lo, float hi) {   // RNE pack, same as f2bf
    unsigned d;
    asm("v_cvt_pk_bf16_f32 %0, %1, %2" : "=v"(d) : "v"(lo), "v"(hi));
    return d;
}

#define GLOAD16(gp, lp) __builtin_amdgcn_global_load_lds( \
    (const __attribute__((address_space(1))) void*)(gp),  \
    (__attribute__((address_space(3))) void*)(lp), 16, 0, 0)

// ---------------- pre-pass: 3 weight transposes only ----------------
__device__ __forceinline__ void tc_tile(
    const float* __restrict__ W, short* __restrict__ Wt, int K, int N,
    int bx, int by, float (*t)[33])
{
    const int tx = threadIdx.x & 31, ty = threadIdx.x >> 5;  // 32 x 8
    const int nt = bx * 32, kt = by * 32;
    #pragma unroll
    for (int j = 0; j < 4; ++j)
        t[ty + 8 * j][tx] = W[(size_t)(kt + ty + 8 * j) * N + nt + tx];
    __syncthreads();
    #pragma unroll
    for (int j = 0; j < 4; ++j)
        Wt[(size_t)(nt + ty + 8 * j) * K + kt + tx] = f2bf(t[tx][ty + 8 * j]);
}

__global__ __launch_bounds__(256) void prepass(
    const float* __restrict__ Wqkv, short* __restrict__ Wqkvt,
    const float* __restrict__ Wq, short* __restrict__ Wqt,
    const float* __restrict__ Wproj, short* __restrict__ Wprojt)
{
    __shared__ float t[32][33];
    const int b = blockIdx.x;
    if (b < 3072) {
        tc_tile(Wqkv, Wqkvt, 1024, 3072, b % 96, b / 96, t);
    } else {
        const int z = b - 3072;
        const float* W = (z < 1024) ? Wq : Wproj;
        short* Wt = (z < 1024) ? Wqt : Wprojt;
        const int zz = z & 1023;
        tc_tile(W, Wt, 1024, 1024, zz & 31, zz >> 5, t);
    }
}

// ---------------- k1k2 GEMM: A = f32 x, reg-staged + cvtpk; B bf16 gload_lds --
// R17 skeleton with WRA moved BEFORE ISSB/ISSA inside each phase: at phase
// entry vmcnt(6) leaves <=6 outstanding (= previous phase's group), so the rA
// set consumed by WRA (loaded two phases back) is complete and the compiler's
// own rA-wait coincides with the phase-entry wait instead of landing after the
// new load issues. Cross-phase safety unchanged: buf(P+1)'s A-region was last
// read at COMPUTE(P-2), two barriers before this write; per-wave DS queue is
// in-order so COMPUTE(P)'s lgkm waits drain the A-writes before barrier(P+1).
// NOTE R19 ERRATA: T5 setprio around GEMM MFMAs REGRESSED (-7 us) — lockstep
// barrier regime (m190 null) + deprioritized staging issue. Attention-only.
__global__ __launch_bounds__(256, 3) void gemm_k1k2(
    const float* __restrict__ x,
    const short* __restrict__ Wqkvt, const float* __restrict__ bqkv,
    const short* __restrict__ Wqt,   const float* __restrict__ bq,
    short* __restrict__ Qb, short* __restrict__ Kb, short* __restrict__ Vtb)
{
    __shared__ __align__(16) char AB[49152];    // A bufs [0,24K), B [24K,48K)

    const int tid = threadIdx.x;
    const int wave = tid >> 6, lane = tid & 63;
    const int q = lane & 15, g = lane >> 4;
    const int wm = wave >> 1, wn = wave & 1;

    const int i = blockIdx.x;
    const char* ArowF; const char* Brow0; const float* bias;
    int bb, blocal, rowOff, bn, mode;
    if (i < 384) {                    // K1: anchors @ Wqkv
        const int c = i & 7, j = i >> 3;
        bn = (j % 24) * 128;
        const int bm = ((j / 24) * 8 + c) * 128;
        bb = bm / ANC; blocal = bm % ANC; rowOff = 0; mode = 0;
        ArowF = (const char*)(x + ((size_t)bb * SC + blocal) * DIMC);
        Brow0 = (const char*)(Wqkvt + (size_t)bn * GK);
        bias = bqkv;
    } else {                          // K2: queries @ Wq
        const int i2 = i - 384;
        const int c = i2 & 7, j = i2 >> 3;
        bn = (j % 8) * 128;
        const int bm = ((j / 8) * 8 + c) * 128;
        bb = bm / QNC; blocal = bm % QNC; rowOff = ANC; mode = 1;
        ArowF = (const char*)(x + ((size_t)bb * SC + ANC + blocal) * DIMC);
        Brow0 = (const char*)(Wqt + (size_t)bn * GK);
        bias = bq;
    }

    int srcF[2], srcB[2], dstOff[2];
    #pragma unroll
    for (int p = 0; p < 2; ++p) {
        const int ca = p * 256 + tid;
        const int row = ca >> 2;
        const int c = (ca & 3) ^ ((row >> 1) & 3);   // pre-swizzled chunk
        srcF[p] = row * 4096 + c * 32;               // f32 source (32B / chunk)
        srcB[p] = row * (GK * 2) + c * 16;           // bf16 source
        dstOff[p] = ca * 16;                         // linear LDS dest
    }

    f32x4 acc[4][4];
    #pragma unroll
    for (int a = 0; a < 4; ++a)
        #pragma unroll
        for (int b2 = 0; b2 < 4; ++b2) acc[a][b2] = (f32x4){0.f, 0.f, 0.f, 0.f};

    const int rc = ((g ^ ((q >> 1) & 3)) << 4);      // lane-constant read chunk

    float4 rA[3][4];   // 3 A-reg sets (all indices compile-time constants)

#define ISSB(bufi, kt) do {                                             \
        char* bb_ = AB + 24576 + (bufi) * 8192;                         \
        GLOAD16(Brow0 + srcB[0] + (kt) * 64, bb_ + dstOff[0]);          \
        GLOAD16(Brow0 + srcB[1] + (kt) * 64, bb_ + dstOff[1]);          \
    } while (0)

#define ISSA(s, kt) do {                                                \
        rA[s][0] = *(const float4*)(ArowF + srcF[0] + (kt) * 128);      \
        rA[s][1] = *(const float4*)(ArowF + srcF[0] + (kt) * 128 + 16); \
        rA[s][2] = *(const float4*)(ArowF + srcF[1] + (kt) * 128);      \
        rA[s][3] = *(const float4*)(ArowF + srcF[1] + (kt) * 128 + 16); \
    } while (0)

#define WRA(bufi, s) do {                                               \
        char* ab_ = AB + (bufi) * 8192;                                 \
        union { s16x8 v; unsigned u[4]; } w0, w1;                       \
        w0.u[0] = cvtpk(rA[s][0].x, rA[s][0].y);                        \
        w0.u[1] = cvtpk(rA[s][0].z, rA[s][0].w);                        \
        w0.u[2] = cvtpk(rA[s][1].x, rA[s][1].y);                        \
        w0.u[3] = cvtpk(rA[s][1].z, rA[s][1].w);                        \
        w1.u[0] = cvtpk(rA[s][2].x, rA[s][2].y);                        \
        w1.u[1] = cvtpk(rA[s][2].z, rA[s][2].w);                        \
        w1.u[2] = cvtpk(rA[s][3].x, rA[s][3].y);                        \
        w1.u[3] = cvtpk(rA[s][3].z, rA[s][3].w);                        \
        *(s16x8*)(ab_ + dstOff[0]) = w0.v;                              \
        *(s16x8*)(ab_ + dstOff[1]) = w1.v;                              \
    } while (0)

#define COMPUTE(bufi) do {                                              \
        const char* ab_ = AB + (bufi) * 8192;                           \
        const char* bb_ = AB + 24576 + (bufi) * 8192;                   \
        s16x8 aF[4], bF[4];                                             \
        _Pragma("unroll")                                               \
        for (int mi = 0; mi < 4; ++mi)                                  \
            aF[mi] = *(const s16x8*)(ab_ + (wm * 64 + mi * 16 + q) * 64 + rc); \
        _Pragma("unroll")                                               \
        for (int ni = 0; ni < 4; ++ni)                                  \
            bF[ni] = *(const s16x8*)(bb_ + (wn * 64 + ni * 16 + q) * 64 + rc); \
        _Pragma("unroll")                                               \
        for (int mi = 0; mi < 4; ++mi)                                  \
            _Pragma("unroll")                                           \
            for (int ni = 0; ni < 4; ++ni)                              \
                acc[mi][ni] = __builtin_amdgcn_mfma_f32_16x16x32_bf16(  \
                    aF[mi], bF[ni], acc[mi][ni], 0, 0, 0);              \
    } while (0)

#define PHF(cb, Bb, Wb, Ws, As, ktB, ktA) do {                          \
        asm volatile("s_waitcnt vmcnt(6)" ::: "memory");                \
        __builtin_amdgcn_s_barrier();                                   \
        WRA(Wb, Ws);          /* rA certified by the entry vmcnt(6) */  \
        ISSB(Bb, ktB);                                                  \
        ISSA(As, ktA);                                                  \
        COMPUTE(cb);                                                    \
    } while (0)

    // prologue: A(0)->set0, B(0), A(1)->set1, B(1), A(2)->set2; drain; write buf0
    ISSA(0, 0);
    ISSB(0, 0); ISSA(1, 1);
    ISSB(1, 1); ISSA(2, 2);
    asm volatile("s_waitcnt vmcnt(0)" ::: "memory");
    WRA(0, 0);
    asm volatile("s_waitcnt lgkmcnt(0)" ::: "memory");

    #pragma unroll 1
    for (int t = 0; t < 27; t += 3) {
        PHF(0, 2, 1, 1, 0, t + 2, t + 3);   // P=t
        PHF(1, 0, 2, 2, 1, t + 3, t + 4);   // P=t+1
        PHF(2, 1, 0, 0, 2, t + 4, t + 5);   // P=t+2
    }
    PHF(0, 2, 1, 1, 0, 29, 30);             // P=27
    PHF(1, 0, 2, 2, 1, 30, 31);             // P=28
    // P=29: write buf(30)=0 from set0 (A(30) certified); issue B(31); compute 2
    asm volatile("s_waitcnt vmcnt(6)" ::: "memory");
    __builtin_amdgcn_s_barrier();
    WRA(0, 0);
    ISSB(1, 31);
    COMPUTE(2);
    // P=30: certify phase-28 group (B(30)+A(31)); write buf(31)=1 from set1
    asm volatile("s_waitcnt vmcnt(2)" ::: "memory");
    __builtin_amdgcn_s_barrier();
    WRA(1, 1);
    COMPUTE(0);
    // P=31: drain all (B(31)); compute buf 1
    asm volatile("s_waitcnt vmcnt(0)" ::: "memory");
    __builtin_amdgcn_s_barrier();
    COMPUTE(1);

#undef PHF
#undef COMPUTE
#undef WRA
#undef ISSA
#undef ISSB

    // epilogue: lane holds C[wm*64+mi*16+4g+r][wn*64+ni*16+q]
    #pragma unroll
    for (int ni = 0; ni < 4; ++ni) {
        const int col = bn + wn * 64 + ni * 16 + q;
        const float bv = bias[col];
        #pragma unroll
        for (int mi = 0; mi < 4; ++mi) {
            const int rl0 = blocal + wm * 64 + mi * 16 + 4 * g;
            if (mode == 1) {
                const int h = col >> 6, d = col & 63;
                const size_t base = ((size_t)(bb * HC + h)) * SC + rowOff + rl0;
                #pragma unroll
                for (int r = 0; r < 4; ++r)
                    Qb[(base + r) * DC + d] = f2bf((acc[mi][ni][r] + bv) * QSCALE);
            } else {
                const int which = col >> 10;
                const int hd = col & 1023;
                const int h = hd >> 6, d = hd & 63;
                const size_t bh = (size_t)(bb * HC + h);
                if (which == 0) {
                    #pragma unroll
                    for (int r = 0; r < 4; ++r)
                        Qb[(bh * SC + rl0 + r) * DC + d] =
                            f2bf((acc[mi][ni][r] + bv) * QSCALE);
                } else if (which == 1) {
                    #pragma unroll
                    for (int r = 0; r < 4; ++r)
                        Kb[(bh * ANC + rl0 + r) * DC + d] = f2bf(acc[mi][ni][r] + bv);
                } else {
                    union { s16x4 v; unsigned long long d8; } pk;
                    #pragma unroll
                    for (int r = 0; r < 4; ++r) pk.v[r] = f2bf(acc[mi][ni][r] + bv);
                    *(unsigned long long*)(Vtb + (bh * DC + d) * ANC + rl0) = pk.d8;
                }
            }
        }
    }
}

// ---------------- proj GEMM: R16/R18 path (A bf16 via gload_lds) --------------
__global__ __launch_bounds__(256) void gemm_proj(
    const short* __restrict__ Abase, const short* __restrict__ Bt,
    const float* __restrict__ bias, float* __restrict__ outF)
{
    __shared__ __align__(16) char AB[49152];

    const int tid = threadIdx.x;
    const int wave = tid >> 6, lane = tid & 63;
    const int q = lane & 15, g = lane >> 4;
    const int wm = wave >> 1, wn = wave & 1;

    const int i = blockIdx.x;
    const int c0 = i & 7, j = i >> 3;
    const int bn = (j % 8) * 128;
    const int bm = ((j / 8) * 8 + c0) * 128;
    const char* Arow0 = (const char*)(Abase + (size_t)bm * GK);
    const char* Brow0 = (const char*)(Bt + (size_t)bn * GK);

    int srcOff[2], dstOff[2];
    #pragma unroll
    for (int p = 0; p < 2; ++p) {
        const int ca = p * 256 + tid;
        const int row = ca >> 2;
        const int c = (ca & 3) ^ ((row >> 1) & 3);
        srcOff[p] = row * (GK * 2) + c * 16;
        dstOff[p] = ca * 16;
    }

    f32x4 acc[4][4];
    #pragma unroll
    for (int a = 0; a < 4; ++a)
        #pragma unroll
        for (int b2 = 0; b2 < 4; ++b2) acc[a][b2] = (f32x4){0.f, 0.f, 0.f, 0.f};

    const int rc = ((g ^ ((q >> 1) & 3)) << 4);

#define STAGE(bufi, kt) do {                                            \
        const int kb_ = (kt) * 64;                                      \
        char* ab_ = AB + (bufi) * 8192;                                 \
        char* bb_ = AB + 24576 + (bufi) * 8192;                         \
        GLOAD16(Arow0 + srcOff[0] + kb_, ab_ + dstOff[0]);              \
        GLOAD16(Arow0 + srcOff[1] + kb_, ab_ + dstOff[1]);              \
        GLOAD16(Brow0 + srcOff[0] + kb_, bb_ + dstOff[0]);              \
        GLOAD16(Brow0 + srcOff[1] + kb_, bb_ + dstOff[1]);              \
    } while (0)

#define COMPUTE(bufi) do {                                              \
        const char* ab_ = AB + (bufi) * 8192;                           \
        const char* bb_ = AB + 24576 + (bufi) * 8192;                   \
        s16x8 aF[4], bF[4];                                             \
        _Pragma("unroll")                                               \
        for (int mi = 0; mi < 4; ++mi)                                  \
            aF[mi] = *(const s16x8*)(ab_ + (wm * 64 + mi * 16 + q) * 64 + rc); \
        _Pragma("unroll")                                               \
        for (int ni = 0; ni < 4; ++ni)                                  \
            bF[ni] = *(const s16x8*)(bb_ + (wn * 64 + ni * 16 + q) * 64 + rc); \
        _Pragma("unroll")                                               \
        for (int mi = 0; mi < 4; ++mi)                                  \
            _Pragma("unroll")                                           \
            for (int ni = 0; ni < 4; ++ni)                              \
                acc[mi][ni] = __builtin_amdgcn_mfma_f32_16x16x32_bf16(  \
                    aF[mi], bF[ni], acc[mi][ni], 0, 0, 0);              \
    } while (0)

#define PHASE4(stb, cb, kt) do {                                        \
        asm volatile("s_waitcnt vmcnt(4)" ::: "memory");                \
        __builtin_amdgcn_s_barrier();                                   \
        STAGE(stb, kt);                                                 \
        COMPUTE(cb);                                                    \
    } while (0)

    STAGE(0, 0);
    STAGE(1, 1);
    #pragma unroll 1
    for (int t = 0; t < 30; t += 3) {
        PHASE4(2, 0, t + 2);
        PHASE4(0, 1, t + 3);
        PHASE4(1, 2, t + 4);
    }
    asm volatile("s_waitcnt vmcnt(4)" ::: "memory");
    __builtin_amdgcn_s_barrier();
    COMPUTE(0);
    asm volatile("s_waitcnt vmcnt(0)" ::: "memory");
    __builtin_amdgcn_s_barrier();
    COMPUTE(1);
#undef PHASE4
#undef STAGE
#undef COMPUTE

    #pragma unroll
    for (int ni = 0; ni < 4; ++ni) {
        const int col = bn + wn * 64 + ni * 16 + q;
        const float bv = bias[col];
        #pragma unroll
        for (int mi = 0; mi < 4; ++mi) {
            const int grow = bm + wm * 64 + mi * 16 + 4 * g;
            #pragma unroll
            for (int r = 0; r < 4; ++r)
                outF[(size_t)(grow + r) * 1024 + col] = acc[mi][ni][r] + bv;
        }
    }
}

// ---------------- persistent-KV bf16 MFMA attention (R16/R18 exact) -----------
__global__ __launch_bounds__(512, 2) void attn_mfma(
    const short* __restrict__ Qb, const short* __restrict__ Kb,
    const short* __restrict__ Vtb, short* __restrict__ Aout)
{
    __shared__ __align__(16) char lds[147456];

    const int tid = threadIdx.x;
    const int wave = tid >> 6, lane = tid & 63;
    const int q = lane & 15, g = lane >> 4;
    const int q7 = q & 7;
    const int G = g ^ q7;
    const int bh = blockIdx.x >> 2;
    const int qc = blockIdx.x & 3;
    const int sbase = qc * 1024 + wave * 128;

    {
        const char* src = (const char*)(Kb + (size_t)bh * ANC * DC);
        #pragma unroll
        for (int l = 0; l < 8; ++l) {
            int i = l * 512 + tid;
            int row = i >> 3, cg = i & 7;
            union { float4 v; unsigned long long d[2]; } u;
            u.v = *(const float4*)(src + (size_t)i * 16);
            int kk = cg >> 2;
            int u0 = (2 * cg) & 7;
            int pc0 = 4 * kk + (u0 & 3);
            int hh = (u0 >> 2) << 3;
            int r7 = row & 7;
            char* dst = lds + row * 128;
            *(unsigned long long*)(dst + ((pc0 ^ r7) << 4) + hh) = u.d[0];
            *(unsigned long long*)(dst + (((pc0 + 1) ^ r7) << 4) + hh) = u.d[1];
        }
    }
    {
        const char* src = (const char*)(Vtb + (size_t)bh * DC * ANC);
        #pragma unroll
        for (int l = 0; l < 8; ++l) {
            int i = l * 512 + tid;
            int row = i >> 6, cg = i & 63;
            union { float4 v; unsigned long long d[2]; } u;
            u.v = *(const float4*)(src + (size_t)i * 16);
            int t2 = cg >> 2;
            int u0 = (2 * cg) & 7;
            int pc0 = 4 * t2 + (u0 & 3);
            int hh = (u0 >> 2) << 3;
            int r7 = row & 7;
            char* dst = lds + 65536 + row * 1024;
            *(unsigned long long*)(dst + ((pc0 ^ r7) << 4) + hh) = u.d[0];
            *(unsigned long long*)(dst + (((pc0 + 1) ^ r7) << 4) + hh) = u.d[1];
        }
    }
    __syncthreads();

    char* slot = lds + 131072 + wave * 2048;
    const int srow = lane >> 2, sc2 = lane & 3;
    const int sr7 = srow & 7;

    const int cgA = 2 * sc2, kkA = cgA >> 2, u0A = (2 * cgA) & 7;
    const int pcA = 4 * kkA + (u0A & 3), hA = (u0A >> 2) << 3;
    const int cgB = cgA + 1, kkB = cgB >> 2, u0B = (2 * cgB) & 7;
    const int pcB = 4 * kkB + (u0B & 3), hB = (u0B >> 2) << 3;
    const int wA0 = srow * 128 + ((pcA ^ sr7) << 4) + hA;
    const int wA1 = srow * 128 + (((pcA + 1) ^ sr7) << 4) + hA;
    const int wB0 = srow * 128 + ((pcB ^ sr7) << 4) + hB;
    const int wB1 = srow * 128 + (((pcB + 1) ^ sr7) << 4) + hB;
    const int wb0 = srow * 128 + (((sc2 * 2 + 0) ^ sr7) << 4);
    const int wb1 = srow * 128 + (((sc2 * 2 + 1) ^ sr7) << 4);
    const int sw = q7 << 4;

    const int off0 = G << 4, off1 = off0 ^ 64;
    const char* kb0 = lds + q * 128 + off0;
    const char* kb1 = lds + q * 128 + off1;
    const char* vregion = lds + 65536;
    const unsigned vo0 = (unsigned)((q +  0) * 1024 + off0);
    const unsigned vo1 = (unsigned)((q + 16) * 1024 + off0);
    const unsigned vo2 = (unsigned)((q + 32) * 1024 + off0);
    const unsigned vo3 = (unsigned)((q + 48) * 1024 + off0);

    const size_t qrow0 = (size_t)bh * SC;

    union { float4 v; unsigned long long d[2]; } gqA0, gqA1, gqB0, gqB1;
    {
        const char* QA = (const char*)(Qb + (qrow0 + sbase) * DC);
        gqA0.v = *(const float4*)(QA + lane * 32);
        gqA1.v = *(const float4*)(QA + lane * 32 + 16);
        const char* QB = QA + 16 * DC * 2;
        gqB0.v = *(const float4*)(QB + lane * 32);
        gqB1.v = *(const float4*)(QB + lane * 32 + 16);
    }

    for (int tp = 0; tp < 4; ++tp) {
        const int s0A = sbase + tp * 32;
        const int s0B = s0A + 16;

        *(unsigned long long*)(slot + wA0) = gqA0.d[0];
        *(unsigned long long*)(slot + wA1) = gqA0.d[1];
        *(unsigned long long*)(slot + wB0) = gqA1.d[0];
        *(unsigned long long*)(slot + wB1) = gqA1.d[1];
        __asm__ __volatile__("" ::: "memory");
        s16x8 qfA0 = *(const s16x8*)(slot + q * 128 + off0);
        s16x8 qfA1 = *(const s16x8*)(slot + q * 128 + off1);
        __asm__ __volatile__("" ::: "memory");
        *(unsigned long long*)(slot + wA0) = gqB0.d[0];
        *(unsigned long long*)(slot + wA1) = gqB0.d[1];
        *(unsigned long long*)(slot + wB0) = gqB1.d[0];
        *(unsigned long long*)(slot + wB1) = gqB1.d[1];
        __asm__ __volatile__("" ::: "memory");
        s16x8 qfB0 = *(const s16x8*)(slot + q * 128 + off0);
        s16x8 qfB1 = *(const s16x8*)(slot + q * 128 + off1);

        s16x8 pfA[16], pfB[16];
        float psA0 = 0.f, psA1 = 0.f, psA2 = 0.f, psA3 = 0.f;
        float psB0 = 0.f, psB1 = 0.f, psB2 = 0.f, psB3 = 0.f;
        __builtin_amdgcn_s_setprio(1);
        #pragma unroll
        for (int t2 = 0; t2 < 16; ++t2) {
            const int be = (2 * t2) * 2048, bo = be + 2048;
            s16x8 kfe0 = *(const s16x8*)(kb0 + be);
            s16x8 kfe1 = *(const s16x8*)(kb1 + be);
            f32x4 sA = (f32x4){0.f, 0.f, 0.f, 0.f};
            sA = __builtin_amdgcn_mfma_f32_16x16x32_bf16(kfe0, qfA0, sA, 0, 0, 0);
            sA = __builtin_amdgcn_mfma_f32_16x16x32_bf16(kfe1, qfA1, sA, 0, 0, 0);
            f32x4 sB = (f32x4){0.f, 0.f, 0.f, 0.f};
            sB = __builtin_amdgcn_mfma_f32_16x16x32_bf16(kfe0, qfB0, sB, 0, 0, 0);
            sB = __builtin_amdgcn_mfma_f32_16x16x32_bf16(kfe1, qfB1, sB, 0, 0, 0);
            s16x8 kfo0 = *(const s16x8*)(kb0 + bo);
            s16x8 kfo1 = *(const s16x8*)(kb1 + bo);
            f32x4 tA = (f32x4){0.f, 0.f, 0.f, 0.f};
            tA = __builtin_amdgcn_mfma_f32_16x16x32_bf16(kfo0, qfA0, tA, 0, 0, 0);
            tA = __builtin_amdgcn_mfma_f32_16x16x32_bf16(kfo1, qfA1, tA, 0, 0, 0);
            f32x4 tB = (f32x4){0.f, 0.f, 0.f, 0.f};
            tB = __builtin_amdgcn_mfma_f32_16x16x32_bf16(kfo0, qfB0, tB, 0, 0, 0);
            tB = __builtin_amdgcn_mfma_f32_16x16x32_bf16(kfo1, qfB1, tB, 0, 0, 0);

            float eA0 = exp2f(sA[0]), eA1 = exp2f(sA[1]);
            float eA2 = exp2f(sA[2]), eA3 = exp2f(sA[3]);
            float fA0 = exp2f(tA[0]), fA1 = exp2f(tA[1]);
            float fA2 = exp2f(tA[2]), fA3 = exp2f(tA[3]);
            psA0 += eA0 + fA0; psA1 += eA1 + fA1;
            psA2 += eA2 + fA2; psA3 += eA3 + fA3;
            float eB0 = exp2f(sB[0]), eB1 = exp2f(sB[1]);
            float eB2 = exp2f(sB[2]), eB3 = exp2f(sB[3]);
            float fB0 = exp2f(tB[0]), fB1 = exp2f(tB[1]);
            float fB2 = exp2f(tB[2]), fB3 = exp2f(tB[3]);
            psB0 += eB0 + fB0; psB1 += eB1 + fB1;
            psB2 += eB2 + fB2; psB3 += eB3 + fB3;

            union { s16x8 v; unsigned u[4]; } pkA, pkB;
            pkA.u[0] = cvtpk(eA0, eA1); pkA.u[1] = cvtpk(eA2, eA3);
            pkA.u[2] = cvtpk(fA0, fA1); pkA.u[3] = cvtpk(fA2, fA3);
            pfA[t2] = pkA.v;
            pkB.u[0] = cvtpk(eB0, eB1); pkB.u[1] = cvtpk(eB2, eB3);
            pkB.u[2] = cvtpk(fB0, fB1); pkB.u[3] = cvtpk(fB2, fB3);
            pfB[t2] = pkB.v;
        }
        __builtin_amdgcn_s_setprio(0);

        {
            const int snext = (tp < 3) ? (s0A + 32) : sbase;
            const char* QA = (const char*)(Qb + (qrow0 + snext) * DC);
            gqA0.v = *(const float4*)(QA + lane * 32);
            gqA1.v = *(const float4*)(QA + lane * 32 + 16);
            const char* QB = QA + 16 * DC * 2;
            gqB0.v = *(const float4*)(QB + lane * 32);
            gqB1.v = *(const float4*)(QB + lane * 32 + 16);
            __asm__ __volatile__("" :
                "+v"(gqA0.v.x), "+v"(gqA0.v.y), "+v"(gqA0.v.z), "+v"(gqA0.v.w),
                "+v"(gqA1.v.x), "+v"(gqA1.v.y), "+v"(gqA1.v.z), "+v"(gqA1.v.w),
                "+v"(gqB0.v.x), "+v"(gqB0.v.y), "+v"(gqB0.v.z), "+v"(gqB0.v.w),
                "+v"(gqB1.v.x), "+v"(gqB1.v.y), "+v"(gqB1.v.z), "+v"(gqB1.v.w));
        }

        float sumA = (psA0 + psA1) + (psA2 + psA3);
        sumA += __shfl_xor(sumA, 16);
        sumA += __shfl_xor(sumA, 32);
        const float rinvA = 1.0f / sumA;
        float sumB = (psB0 + psB1) + (psB2 + psB3);
        sumB += __shfl_xor(sumB, 16);
        sumB += __shfl_xor(sumB, 32);
        const float rinvB = 1.0f / sumB;

        f32x4 oaccA[4], oaccB[4];
        #pragma unroll
        for (int md = 0; md < 4; ++md) {
            oaccA[md] = (f32x4){0.f, 0.f, 0.f, 0.f};
            oaccB[md] = (f32x4){0.f, 0.f, 0.f, 0.f};
        }
        __builtin_amdgcn_s_setprio(1);
        #pragma unroll
        for (int t2 = 0; t2 < 16; ++t2) {
            const unsigned tx = (unsigned)(t2 << 6);
            s16x8 vf0 = *(const s16x8*)(vregion + (vo0 ^ tx));
            oaccA[0] = __builtin_amdgcn_mfma_f32_16x16x32_bf16(vf0, pfA[t2], oaccA[0], 0, 0, 0);
            oaccB[0] = __builtin_amdgcn_mfma_f32_16x16x32_bf16(vf0, pfB[t2], oaccB[0], 0, 0, 0);
            s16x8 vf1 = *(const s16x8*)(vregion + (vo1 ^ tx));
            oaccA[1] = __builtin_amdgcn_mfma_f32_16x16x32_bf16(vf1, pfA[t2], oaccA[1], 0, 0, 0);
            oaccB[1] = __builtin_amdgcn_mfma_f32_16x16x32_bf16(vf1, pfB[t2], oaccB[1], 0, 0, 0);
            s16x8 vf2 = *(const s16x8*)(vregion + (vo2 ^ tx));
            oaccA[2] = __builtin_amdgcn_mfma_f32_16x16x32_bf16(vf2, pfA[t2], oaccA[2], 0, 0, 0);
            oaccB[2] = __builtin_amdgcn_mfma_f32_16x16x32_bf16(vf2, pfB[t2], oaccB[2], 0, 0, 0);
            s16x8 vf3 = *(const s16x8*)(vregion + (vo3 ^ tx));
            oaccA[3] = __builtin_amdgcn_mfma_f32_16x16x32_bf16(vf3, pfA[t2], oaccA[3], 0, 0, 0);
            oaccB[3] = __builtin_amdgcn_mfma_f32_16x16x32_bf16(vf3, pfB[t2], oaccB[3], 0, 0, 0);
        }
        __builtin_amdgcn_s_setprio(0);

        __asm__ __volatile__("" ::: "memory");
        #pragma unroll
        for (int md = 0; md < 4; ++md) {
            union { unsigned long long d; unsigned u[2]; } ow;
            ow.u[0] = cvtpk(oaccA[md][0] * rinvA, oaccA[md][1] * rinvA);
            ow.u[1] = cvtpk(oaccA[md][2] * rinvA, oaccA[md][3] * rinvA);
            *(unsigned long long*)(slot + q * 128 + ((32 * md + 8 * g) ^ sw)) = ow.d;
        }
        __asm__ __volatile__("" ::: "memory");
        {
            float4 o0 = *(const float4*)(slot + wb0);
            float4 o1 = *(const float4*)(slot + wb1);
            char* Op = (char*)Aout +
                (((size_t)(bh >> 4) * SC + s0A + srow) * DIMC + (bh & 15) * DC) * 2 +
                sc2 * 32;
            *(float4*)(Op) = o0;
            *(float4*)(Op + 16) = o1;
        }
        __asm__ __volatile__("" ::: "memory");
        #pragma unroll
        for (int md = 0; md < 4; ++md) {
            union { unsigned long long d; unsigned u[2]; } ow;
            ow.u[0] = cvtpk(oaccB[md][0] * rinvB, oaccB[md][1] * rinvB);
            ow.u[1] = cvtpk(oaccB[md][2] * rinvB, oaccB[md][3] * rinvB);
            *(unsigned long long*)(slot + q * 128 + ((32 * md + 8 * g) ^ sw)) = ow.d;
        }
        __asm__ __volatile__("" ::: "memory");
        {
            float4 o0 = *(const float4*)(slot + wb0);
            float4 o1 = *(const float4*)(slot + wb1);
            char* Op = (char*)Aout +
                (((size_t)(bh >> 4) * SC + s0B + srow) * DIMC + (bh & 15) * DC) * 2 +
                sc2 * 32;
            *(float4*)(Op) = o0;
            *(float4*)(Op + 16) = o1;
        }
    }
}

// ---------------- launcher ----------------
extern "C" void kernel_launch(void* const* d_in, const int* in_sizes, int n_in,
                              void* d_out, int out_size, void* d_ws, size_t ws_size,
                              hipStream_t stream)
{
    (void)in_sizes; (void)n_in; (void)out_size; (void)ws_size;

    const float* x     = (const float*)d_in[0];
    const float* Wqkv  = (const float*)d_in[1];
    const float* bqkv  = (const float*)d_in[2];
    const float* Wq    = (const float*)d_in[3];
    const float* bq    = (const float*)d_in[4];
    const float* Wproj = (const float*)d_in[5];
    const float* bproj = (const float*)d_in[6];

    // d_out scratch: [unused 33.5MB | Qb bf16 33.5MB] (dead before proj writes)
    short* Qb = (short*)d_out + (size_t)16777216;
    short* Kb     = (short*)d_ws;
    short* Vtb    = Kb  + (size_t)2097152;
    short* Ab     = Vtb + (size_t)2097152;
    short* Wqkvt  = Ab  + (size_t)16777216;
    short* Wqt    = Wqkvt + (size_t)3145728;
    short* Wprojt = Wqt   + (size_t)1048576;

    // pre-pass: weight transposes only (k1k2 reads f32 x directly)
    prepass<<<dim3(5120), dim3(256), 0, stream>>>(
        Wqkv, Wqkvt, Wq, Wqt, Wproj, Wprojt);

    // K1+K2 fused: anchors @ Wqkv -> Qb/Kb/Vtb, queries @ Wq -> Qb (A = f32 x)
    gemm_k1k2<<<dim3(1280), dim3(256), 0, stream>>>(
        x, Wqkvt, bqkv, Wqt, bq, Qb, Kb, Vtb);

    // K3: persistent-KV MFMA attention -> Ab (bf16)
    attn_mfma<<<dim3(256), dim3(512), 0, stream>>>(Qb, Kb, Vtb, Ab);

    // K4: Ab @ Wproj + bproj -> d_out (fp32)
    gemm_proj<<<dim3(1024), dim3(256), 0, stream>>>(Ab, Wprojt, bproj, (float*)d_out);
}